// Round 4
// baseline (78.352 us; speedup 1.0000x reference)
//
#include <hip/hip_runtime.h>
#include <hip/hip_bf16.h>

#define PAD_IDX 0
#define SEQ_L 64
#define ROWS_PER_BLOCK 128
#define THREADS 256
// per-row LDS stride in int4 units: 16 data + 1 pad
#define ROW_STRIDE4 17

typedef int   v4i __attribute__((ext_vector_type(4)));
typedef uint  v4u __attribute__((ext_vector_type(4)));
typedef float v4f __attribute__((ext_vector_type(4)));

__device__ __forceinline__ float bf16_lo(unsigned int w) {
    return __uint_as_float(w << 16);
}
__device__ __forceinline__ float bf16_hi(unsigned int w) {
    return __uint_as_float(w & 0xffff0000u);
}

// ---- Pass 1: convert fp32 table -> packed bf16 table in workspace (stays in L2).
__global__ __launch_bounds__(THREADS) void convert_bf16_kernel(
    const float* __restrict__ emb, ushort* __restrict__ tab, int n /* elements */)
{
    int i4 = (blockIdx.x * THREADS + threadIdx.x) * 4;
    if (i4 + 3 < n) {
        float4 v = *reinterpret_cast<const float4*>(emb + i4);
        ushort4 o;
        o.x = __bfloat16_as_ushort(__float2bfloat16(v.x));
        o.y = __bfloat16_as_ushort(__float2bfloat16(v.y));
        o.z = __bfloat16_as_ushort(__float2bfloat16(v.z));
        o.w = __bfloat16_as_ushort(__float2bfloat16(v.w));
        *reinterpret_cast<ushort4*>(tab + i4) = o;
    } else if (i4 < n) {
        for (int k = i4; k < n; ++k)
            tab[k] = __bfloat16_as_ushort(__float2bfloat16(emb[k]));
    }
}

// ---- Pass 2: gather from bf16 table. 2 lanes per row, 16B per gather.
__global__ __launch_bounds__(THREADS) void visit_encoder_bf16v2_kernel(
    const int* __restrict__ code_ids,
    const v4u* __restrict__ tab,     // bf16 table, row = 32B = 2 x v4u
    float* __restrict__ out,
    int B, int n_codes4)
{
    __shared__ v4i lcodes[ROWS_PER_BLOCK * ROW_STRIDE4];  // 34816 B

    const int t = threadIdx.x;
    const int block_row0 = blockIdx.x * ROWS_PER_BLOCK;

    // Stage 128 rows x 64 codes = 2048 int4, nontemporal (don't evict table).
    const v4i* src4 = reinterpret_cast<const v4i*>(code_ids);
    const int base4 = blockIdx.x * (ROWS_PER_BLOCK * SEQ_L / 4);
    #pragma unroll
    for (int k = 0; k < 8; ++k) {
        int j = t + THREADS * k;                 // 0..2047
        int gj = base4 + j;
        if (gj >= n_codes4) gj = n_codes4 - 1;   // tail clamp (codes remain valid ids)
        v4i v = __builtin_nontemporal_load(src4 + gj);
        lcodes[(j >> 4) * ROW_STRIDE4 + (j & 15)] = v;
    }
    __syncthreads();

    const int r  = t >> 1;          // 0..127 row within block
    const int d8 = t & 1;           // half-row: dims 8*d8 .. 8*d8+7
    const v4u* tbase = tab + d8;    // row stride = 2 v4u

    float acc[8] = {0.f,0.f,0.f,0.f,0.f,0.f,0.f,0.f};
    int cnt = 0;

    // 4 batches of 16 codes; 16 x 16B gathers in flight per batch.
    #pragma unroll
    for (int b = 0; b < 4; ++b) {
        int cs[16];
        #pragma unroll
        for (int q = 0; q < 4; ++q) {
            v4i c4 = lcodes[r * ROW_STRIDE4 + b * 4 + q];
            cs[q*4+0] = c4.x; cs[q*4+1] = c4.y; cs[q*4+2] = c4.z; cs[q*4+3] = c4.w;
        }
        v4u e[16];
        #pragma unroll
        for (int u = 0; u < 16; ++u) {
            e[u] = tbase[(size_t)cs[u] * 2];     // global_load_dwordx2... dwordx4, 16 in flight
        }
        #pragma unroll
        for (int u = 0; u < 16; ++u) {
            float m = (cs[u] != PAD_IDX) ? 1.0f : 0.0f;
            acc[0] = fmaf(bf16_lo(e[u].x), m, acc[0]);
            acc[1] = fmaf(bf16_hi(e[u].x), m, acc[1]);
            acc[2] = fmaf(bf16_lo(e[u].y), m, acc[2]);
            acc[3] = fmaf(bf16_hi(e[u].y), m, acc[3]);
            acc[4] = fmaf(bf16_lo(e[u].z), m, acc[4]);
            acc[5] = fmaf(bf16_hi(e[u].z), m, acc[5]);
            acc[6] = fmaf(bf16_lo(e[u].w), m, acc[6]);
            acc[7] = fmaf(bf16_hi(e[u].w), m, acc[7]);
            cnt += (cs[u] != PAD_IDX);
        }
    }

    const int row = block_row0 + r;
    if (row < B) {
        float inv = 1.0f / fmaxf((float)cnt, 1.0f);
        v4f o0, o1;
        o0.x = acc[0]*inv; o0.y = acc[1]*inv; o0.z = acc[2]*inv; o0.w = acc[3]*inv;
        o1.x = acc[4]*inv; o1.y = acc[5]*inv; o1.z = acc[6]*inv; o1.w = acc[7]*inv;
        v4f* op = reinterpret_cast<v4f*>(out + (size_t)row * 16 + d8 * 8);
        __builtin_nontemporal_store(o0, op);
        __builtin_nontemporal_store(o1, op + 1);
    }
}

// ---- Fallback: direct fp32 gather if ws too small.
__global__ __launch_bounds__(THREADS) void visit_encoder_f32_kernel(
    const int* __restrict__ code_ids,
    const float* __restrict__ emb,
    float* __restrict__ out,
    int B, int n_codes4)
{
    __shared__ int4 lcodes[64 * ROW_STRIDE4];
    const int t = threadIdx.x;
    const int block_row0 = blockIdx.x * 64;
    const int4* src4 = reinterpret_cast<const int4*>(code_ids);
    const int base4 = blockIdx.x * (64 * SEQ_L / 4);
    #pragma unroll
    for (int k = 0; k < 4; ++k) {
        int j = t + THREADS * k;
        int gj = base4 + j;
        if (gj >= n_codes4) gj = n_codes4 - 1;
        lcodes[(j >> 4) * ROW_STRIDE4 + (j & 15)] = src4[gj];
    }
    __syncthreads();
    const int r  = t >> 2;
    const int d4 = t & 3;
    const float4* ebase = reinterpret_cast<const float4*>(emb) + d4;
    float4 acc = make_float4(0.f, 0.f, 0.f, 0.f);
    int cnt = 0;
    #pragma unroll
    for (int l4 = 0; l4 < 16; l4 += 2) {
        int4 ca = lcodes[r * ROW_STRIDE4 + l4];
        int4 cb = lcodes[r * ROW_STRIDE4 + l4 + 1];
        int cs[8] = {ca.x, ca.y, ca.z, ca.w, cb.x, cb.y, cb.z, cb.w};
        float4 e[8];
        #pragma unroll
        for (int u = 0; u < 8; ++u) e[u] = ebase[(size_t)cs[u] * 4];
        #pragma unroll
        for (int u = 0; u < 8; ++u) {
            float m = (cs[u] != PAD_IDX) ? 1.0f : 0.0f;
            acc.x = fmaf(e[u].x, m, acc.x);
            acc.y = fmaf(e[u].y, m, acc.y);
            acc.z = fmaf(e[u].z, m, acc.z);
            acc.w = fmaf(e[u].w, m, acc.w);
            cnt += (cs[u] != PAD_IDX);
        }
    }
    const int row = block_row0 + r;
    if (row < B) {
        float inv = 1.0f / fmaxf((float)cnt, 1.0f);
        float4 o;
        o.x = acc.x * inv; o.y = acc.y * inv; o.z = acc.z * inv; o.w = acc.w * inv;
        reinterpret_cast<float4*>(out)[(size_t)row * 4 + d4] = o;
    }
}

extern "C" void kernel_launch(void* const* d_in, const int* in_sizes, int n_in,
                              void* d_out, int out_size, void* d_ws, size_t ws_size,
                              hipStream_t stream) {
    const int*   code_ids = (const int*)d_in[0];
    const float* emb      = (const float*)d_in[1];
    float*       out      = (float*)d_out;

    const int total_codes = in_sizes[0];        // B * L
    const int B = total_codes / SEQ_L;
    const int n_codes4 = total_codes / 4;
    const int emb_elems = in_sizes[1];          // NUM_CODES * DIM

    const size_t tab_bytes = (size_t)emb_elems * sizeof(ushort);
    if (ws_size >= tab_bytes) {
        ushort* tab = (ushort*)d_ws;
        int n4 = (emb_elems + 3) / 4;
        convert_bf16_kernel<<<dim3((n4 + THREADS - 1) / THREADS), dim3(THREADS), 0, stream>>>(
            emb, tab, emb_elems);
        const int grid = (B + ROWS_PER_BLOCK - 1) / ROWS_PER_BLOCK;
        visit_encoder_bf16v2_kernel<<<dim3(grid), dim3(THREADS), 0, stream>>>(
            code_ids, (const v4u*)tab, out, B, n_codes4);
    } else {
        const int grid = (B + 63) / 64;
        visit_encoder_f32_kernel<<<dim3(grid), dim3(THREADS), 0, stream>>>(
            code_ids, emb, out, B, n_codes4);
    }
}